// Round 1
// baseline (1909.192 us; speedup 1.0000x reference)
//
#include <hip/hip_runtime.h>
#include <math.h>

// Problem constants (from reference)
#define T_TOK 16384
#define DIM   768
#define HID   3072
#define NE    5
#define BM    32     // rows (expert-token pairs) per block
#define BJ    64     // HID chunk per j-iteration
#define EPS64 2.2204460492503131e-16f

typedef short bf16x8 __attribute__((ext_vector_type(8)));  // 8 bf16 in 4 VGPRs
typedef float f32x4  __attribute__((ext_vector_type(4)));

#define MFMA(A, B, C) __builtin_amdgcn_mfma_f32_16x16x32_bf16((A), (B), (C), 0, 0, 0)

__device__ __forceinline__ unsigned short f2bf(float f) {
    unsigned int u = __float_as_uint(f);
    unsigned int r = (u + 0x7fffu + ((u >> 16) & 1u)) >> 16;  // RNE
    return (unsigned short)r;
}

// ---------------- cast x fp32 -> bf16 ----------------
__global__ void cast_x_kernel(const float* __restrict__ x, unsigned short* __restrict__ xb) {
    int i = (blockIdx.x * 256 + threadIdx.x) * 4;
    if (i >= T_TOK * DIM) return;
    float4 v = *reinterpret_cast<const float4*>(x + i);
    ushort4 o;
    o.x = f2bf(v.x); o.y = f2bf(v.y); o.z = f2bf(v.z); o.w = f2bf(v.w);
    *reinterpret_cast<ushort4*>(xb + i) = o;
}

// ---------------- pre-swizzle W1 into B-fragment order ----------------
// W1s[e][nt(0..191)][kk(0..23)][lane][j] = W1[e][k][n],
//   k = kk*32 + (lane>>4)*8 + j  (DIM axis), n = nt*16 + (lane&15) (HID axis)
__global__ void prep_w1_kernel(const float* __restrict__ W1, unsigned short* __restrict__ W1s) {
    long long idx = (long long)blockIdx.x * 256 + threadIdx.x;
    if (idx >= (long long)NE * DIM * HID) return;
    int j = idx & 7;
    int l = (idx >> 3) & 63;
    long long rest = idx >> 9;
    int kk = (int)(rest % 24); rest /= 24;
    int nt = (int)(rest % 192);
    int e  = (int)(rest / 192);
    int k = kk * 32 + (l >> 4) * 8 + j;
    int n = nt * 16 + (l & 15);
    W1s[idx] = f2bf(W1[((long long)e * DIM + k) * HID + n]);
}

// W2s[e][nt(0..47)][kk(0..95)][lane][j] = W2[e][k][n],
//   k = kk*32 + (lane>>4)*8 + j (HID axis), n = nt*16 + (lane&15) (DIM axis)
__global__ void prep_w2_kernel(const float* __restrict__ W2, unsigned short* __restrict__ W2s) {
    long long idx = (long long)blockIdx.x * 256 + threadIdx.x;
    if (idx >= (long long)NE * HID * DIM) return;
    int j = idx & 7;
    int l = (idx >> 3) & 63;
    long long rest = idx >> 9;
    int kk = (int)(rest % 96); rest /= 96;
    int nt = (int)(rest % 48);
    int e  = (int)(rest / 48);
    int k = kk * 32 + (l >> 4) * 8 + j;
    int n = nt * 16 + (l & 15);
    W2s[idx] = f2bf(W2[((long long)e * HID + k) * DIM + n]);
}

// ---------------- gating: fp64 logits, top-2, softmax, bucket scatter ----------------
__global__ void gate_kernel(const float* __restrict__ x, const float* __restrict__ wg,
                            int* __restrict__ counts, int* __restrict__ btok,
                            float* __restrict__ bgate) {
    int wv = threadIdx.x >> 6, lane = threadIdx.x & 63;
    int t = blockIdx.x * 4 + wv;
    double a0 = 0, a1 = 0, a2 = 0, a3 = 0, a4 = 0;
    for (int i = 0; i < 12; ++i) {
        int d = i * 64 + lane;
        double xv = (double)x[(long long)t * DIM + d];
        a0 += xv * (double)wg[d * NE + 0];
        a1 += xv * (double)wg[d * NE + 1];
        a2 += xv * (double)wg[d * NE + 2];
        a3 += xv * (double)wg[d * NE + 3];
        a4 += xv * (double)wg[d * NE + 4];
    }
    for (int off = 32; off; off >>= 1) {
        a0 += __shfl_down(a0, off);
        a1 += __shfl_down(a1, off);
        a2 += __shfl_down(a2, off);
        a3 += __shfl_down(a3, off);
        a4 += __shfl_down(a4, off);
    }
    if (lane == 0) {
        double v[NE] = {a0, a1, a2, a3, a4};
        int i0 = 0;
        for (int e = 1; e < NE; ++e) if (v[e] > v[i0]) i0 = e;
        int i1 = -1;
        for (int e = 0; e < NE; ++e) {
            if (e == i0) continue;
            if (i1 < 0 || v[e] > v[i1]) i1 = e;
        }
        // softmax over (v[i0] >= v[i1])
        float e1 = expf((float)(v[i1] - v[i0]));
        float g0 = 1.0f / (1.0f + e1);
        float g1 = e1 * g0;
        int p0 = atomicAdd(&counts[i0], 1);
        btok[i0 * T_TOK + p0] = t;  bgate[i0 * T_TOK + p0] = g0;
        int p1 = atomicAdd(&counts[i1], 1);
        btok[i1 * T_TOK + p1] = t;  bgate[i1 * T_TOK + p1] = g1;
    }
}

// ---------------- fused expert MLP (bf16 MFMA) ----------------
// grid (512, NE), 512 threads (8 waves). Block handles BM=32 gathered rows of expert e.
// Per j-chunk (64 HID cols): step a: h = gelu(x@W1 + b1)   (each wave one 16x16 tile)
//                            step b: y(acc) += h @ W2chunk (wave owns 96 of 768 out cols)
__global__ __launch_bounds__(512) void expert_kernel(
    const unsigned short* __restrict__ xb, const unsigned short* __restrict__ W1s,
    const unsigned short* __restrict__ W2s, const float* __restrict__ b1,
    const float* __restrict__ b2, const int* __restrict__ counts,
    const int* __restrict__ btok, const float* __restrict__ bgate,
    float* __restrict__ out) {
    __shared__ __align__(16) unsigned short xs[BM][776];  // +8 pad
    __shared__ __align__(16) unsigned short hs[BM][72];   // +8 pad
    __shared__ int   st[BM];
    __shared__ float sg[BM];

    const int e = blockIdx.y;
    const int cnt = counts[e];
    const int m0 = blockIdx.x * BM;
    if (m0 >= cnt) return;

    const int tid = threadIdx.x;
    const int wv = tid >> 6, lane = tid & 63;
    const int col = lane & 15, quad = lane >> 4;

    if (tid < BM) {
        int pos = m0 + tid;
        if (pos < cnt) {
            st[tid] = btok[e * T_TOK + pos];
            sg[tid] = bgate[e * T_TOK + pos];
        } else {
            st[tid] = 0;
            sg[tid] = 0.0f;
        }
    }
    __syncthreads();

    // stage x rows (gather) into LDS: 16 threads/row, 48 bf16 each
    {
        int r = tid >> 4, seg = tid & 15;
        int t = st[r];
        const unsigned short* src = xb + (long long)t * DIM + seg * 48;
        unsigned short* dst = &xs[r][seg * 48];
        #pragma unroll
        for (int i = 0; i < 6; ++i)
            *reinterpret_cast<bf16x8*>(dst + i * 8) =
                *reinterpret_cast<const bf16x8*>(src + i * 8);
    }
    __syncthreads();

    const int mt_a = wv & 1;   // step-a m-tile
    const int ntl  = wv >> 1;  // step-a n-tile within chunk (0..3)

    f32x4 acc[2][6];
    #pragma unroll
    for (int i = 0; i < 2; ++i)
        #pragma unroll
        for (int j = 0; j < 6; ++j)
            acc[i][j] = (f32x4){0.f, 0.f, 0.f, 0.f};

    const unsigned short* arow = &xs[mt_a * 16 + col][quad * 8];

    for (int jc = 0; jc < HID / BJ; ++jc) {
        // ---- step a: one 16x16 h tile per wave, K = 768 (two chains for ILP)
        f32x4 c0 = (f32x4){0.f, 0.f, 0.f, 0.f};
        f32x4 c1 = (f32x4){0.f, 0.f, 0.f, 0.f};
        const unsigned short* bpa =
            W1s + (((long long)e * 192 + jc * 4 + ntl) * 24) * 512 + lane * 8;
        #pragma unroll
        for (int kk = 0; kk < 24; kk += 2) {
            bf16x8 av0 = *reinterpret_cast<const bf16x8*>(arow + kk * 32);
            bf16x8 bv0 = *reinterpret_cast<const bf16x8*>(bpa + kk * 512);
            c0 = MFMA(av0, bv0, c0);
            bf16x8 av1 = *reinterpret_cast<const bf16x8*>(arow + kk * 32 + 32);
            bf16x8 bv1 = *reinterpret_cast<const bf16x8*>(bpa + (kk + 1) * 512);
            c1 = MFMA(av1, bv1, c1);
        }
        f32x4 c = c0 + c1;

        __syncthreads();  // previous step-b hs reads done
        // gelu epilogue, write h (bf16) to LDS in row-major [token][hid]
        {
            int jg = jc * 64 + ntl * 16 + col;
            float bias = b1[e * HID + jg];
            #pragma unroll
            for (int r = 0; r < 4; ++r) {
                int row = mt_a * 16 + quad * 4 + r;
                float v = c[r] + bias;
                float gl = 0.5f * v * (1.0f + erff(v * 0.70710678118654752f));
                hs[row][ntl * 16 + col] = f2bf(gl);
            }
        }
        __syncthreads();  // hs complete

        // ---- step b: acc += h @ W2chunk ; wave owns cols [wv*96, wv*96+96)
        bf16x8 af[2][2];
        #pragma unroll
        for (int mt = 0; mt < 2; ++mt)
            #pragma unroll
            for (int kb = 0; kb < 2; ++kb)
                af[mt][kb] = *reinterpret_cast<const bf16x8*>(
                    &hs[mt * 16 + col][kb * 32 + quad * 8]);

        const unsigned short* bpb =
            W2s + (((long long)e * 48 + wv * 6) * 96 + jc * 2) * 512 + lane * 8;
        #pragma unroll
        for (int ntb = 0; ntb < 6; ++ntb) {
            #pragma unroll
            for (int kb = 0; kb < 2; ++kb) {
                bf16x8 bv = *reinterpret_cast<const bf16x8*>(bpb + (ntb * 96 + kb) * 512);
                acc[0][ntb] = MFMA(af[0][kb], bv, acc[0][ntb]);
                acc[1][ntb] = MFMA(af[1][kb], bv, acc[1][ntb]);
            }
        }
    }

    // ---- epilogue: out[t] += g * exp(y + b2)
    #pragma unroll
    for (int mt = 0; mt < 2; ++mt) {
        #pragma unroll
        for (int r = 0; r < 4; ++r) {
            int row = mt * 16 + quad * 4 + r;
            int t = st[row];
            float g = sg[row];
            if (g > 0.0f) {
                #pragma unroll
                for (int ntb = 0; ntb < 6; ++ntb) {
                    int cg = wv * 96 + ntb * 16 + col;
                    float v = acc[mt][ntb][r] + b2[e * DIM + cg];
                    atomicAdd(out + (long long)t * DIM + cg, g * expf(v));
                }
            }
        }
    }
}

// ---------------- final: out = log(acc), eps guard ----------------
__global__ void log_kernel(float* __restrict__ out, int n) {
    int i = blockIdx.x * 256 + threadIdx.x;
    if (i < n) {
        float v = out[i];
        out[i] = logf(v == 0.0f ? EPS64 : v);
    }
}

extern "C" void kernel_launch(void* const* d_in, const int* in_sizes, int n_in,
                              void* d_out, int out_size, void* d_ws, size_t ws_size,
                              hipStream_t stream) {
    const float* x  = (const float*)d_in[0];
    const float* wg = (const float*)d_in[1];
    const float* W1 = (const float*)d_in[2];
    const float* b1 = (const float*)d_in[3];
    const float* W2 = (const float*)d_in[4];
    const float* b2 = (const float*)d_in[5];
    float* out = (float*)d_out;

    // workspace layout (~73 MB)
    char* ws = (char*)d_ws;
    int*            counts = (int*)ws;                                   // 256 B
    int*            btok   = (int*)(ws + 256);                           // 320 KB
    float*          bgate  = (float*)(ws + 256 + 327680);                // 320 KB
    unsigned short* xb     = (unsigned short*)(ws + 256 + 2 * 327680);   // 24 MB
    unsigned short* W1s    = xb + (size_t)T_TOK * DIM;                   // 22.5 MB
    unsigned short* W2s    = W1s + (size_t)NE * DIM * HID;               // 22.5 MB

    hipMemsetAsync(counts, 0, 256, stream);
    hipMemsetAsync(out, 0, (size_t)out_size * sizeof(float), stream);

    cast_x_kernel<<<(T_TOK * DIM / 4 + 255) / 256, 256, 0, stream>>>(x, xb);
    prep_w1_kernel<<<(int)(((long long)NE * DIM * HID + 255) / 256), 256, 0, stream>>>(W1, W1s);
    prep_w2_kernel<<<(int)(((long long)NE * HID * DIM + 255) / 256), 256, 0, stream>>>(W2, W2s);
    gate_kernel<<<T_TOK / 4, 256, 0, stream>>>(x, wg, counts, btok, bgate);

    expert_kernel<<<dim3(T_TOK / BM, NE), 512, 0, stream>>>(
        xb, W1s, W2s, b1, b2, counts, btok, bgate, out);

    log_kernel<<<(out_size + 255) / 256, 256, 0, stream>>>(out, out_size);
}

// Round 2
// 1521.829 us; speedup vs baseline: 1.2545x; 1.2545x over previous
//
#include <hip/hip_runtime.h>
#include <math.h>

// Problem constants (from reference)
#define T_TOK 16384
#define DIM   768
#define HID   3072
#define NE    5
#define BM    64     // rows (expert-token pairs) per block
#define BJ    128    // HID chunk per j-iteration
#define NJC   (HID / BJ)   // 24
#define EPS64 2.2204460492503131e-16f

typedef short bf16x8  __attribute__((ext_vector_type(8)));   // 8 bf16 in 4 VGPRs
typedef float f32x4   __attribute__((ext_vector_type(4)));
typedef float f32x16  __attribute__((ext_vector_type(16)));

#define MFMA32(A, B, C) __builtin_amdgcn_mfma_f32_32x32x16_bf16((A), (B), (C), 0, 0, 0)

__device__ __forceinline__ unsigned short f2bf(float f) {
    unsigned int u = __float_as_uint(f);
    unsigned int r = (u + 0x7fffu + ((u >> 16) & 1u)) >> 16;  // RNE
    return (unsigned short)r;
}

// ---------------- cast x fp32 -> bf16 ----------------
__global__ void cast_x_kernel(const float* __restrict__ x, unsigned short* __restrict__ xb) {
    int i = (blockIdx.x * 256 + threadIdx.x) * 4;
    if (i >= T_TOK * DIM) return;
    float4 v = *reinterpret_cast<const float4*>(x + i);
    ushort4 o;
    o.x = f2bf(v.x); o.y = f2bf(v.y); o.z = f2bf(v.z); o.w = f2bf(v.w);
    *reinterpret_cast<ushort4*>(xb + i) = o;
}

// ---------------- pre-swizzle W1 into 32x32x16 B-fragment order ----------------
// group g = ((e*96 + nt2)*48 + kf); W1s[g*512 + lane*8 + j] = bf16(W1[e][k][n])
//   n = nt2*32 + (lane&31)  (HID axis), k = kf*16 + (lane>>5)*8 + j  (DIM axis)
// One wave per group: reads are 2 x 128B cachelines per j-step, writes fully coalesced.
__global__ void prep_w1_kernel(const float* __restrict__ W1, unsigned short* __restrict__ W1s) {
    int g = blockIdx.x * 4 + (threadIdx.x >> 6);
    int lane = threadIdx.x & 63;
    int kf = g % 48;
    int rest = g / 48;
    int nt2 = rest % 96;
    int e = rest / 96;
    int n = nt2 * 32 + (lane & 31);
    int k0 = kf * 16 + (lane >> 5) * 8;
    const float* src = W1 + ((size_t)e * DIM + k0) * HID + n;
    bf16x8 v;
    #pragma unroll
    for (int j = 0; j < 8; ++j) v[j] = (short)f2bf(src[(size_t)j * HID]);
    *reinterpret_cast<bf16x8*>(W1s + ((size_t)g * 64 + lane) * 8) = v;
}

// group g = ((e*24 + nt2)*192 + kf); W2s[g*512 + lane*8 + j] = bf16(W2[e][k][n])
//   n = nt2*32 + (lane&31)  (DIM axis), k = kf*16 + (lane>>5)*8 + j  (HID axis)
__global__ void prep_w2_kernel(const float* __restrict__ W2, unsigned short* __restrict__ W2s) {
    int g = blockIdx.x * 4 + (threadIdx.x >> 6);
    int lane = threadIdx.x & 63;
    int kf = g % 192;
    int rest = g / 192;
    int nt2 = rest % 24;
    int e = rest / 24;
    int n = nt2 * 32 + (lane & 31);
    int k0 = kf * 16 + (lane >> 5) * 8;
    const float* src = W2 + ((size_t)e * HID + k0) * DIM + n;
    bf16x8 v;
    #pragma unroll
    for (int j = 0; j < 8; ++j) v[j] = (short)f2bf(src[(size_t)j * DIM]);
    *reinterpret_cast<bf16x8*>(W2s + ((size_t)g * 64 + lane) * 8) = v;
}

// ---------------- gating: fp64 logits, top-2, softmax, bucket scatter ----------------
__global__ void gate_kernel(const float* __restrict__ x, const float* __restrict__ wg,
                            int* __restrict__ counts, int* __restrict__ btok,
                            float* __restrict__ bgate) {
    int wv = threadIdx.x >> 6, lane = threadIdx.x & 63;
    int t = blockIdx.x * 4 + wv;
    double a0 = 0, a1 = 0, a2 = 0, a3 = 0, a4 = 0;
    for (int i = 0; i < 12; ++i) {
        int d = i * 64 + lane;
        double xv = (double)x[(long long)t * DIM + d];
        a0 += xv * (double)wg[d * NE + 0];
        a1 += xv * (double)wg[d * NE + 1];
        a2 += xv * (double)wg[d * NE + 2];
        a3 += xv * (double)wg[d * NE + 3];
        a4 += xv * (double)wg[d * NE + 4];
    }
    for (int off = 32; off; off >>= 1) {
        a0 += __shfl_down(a0, off);
        a1 += __shfl_down(a1, off);
        a2 += __shfl_down(a2, off);
        a3 += __shfl_down(a3, off);
        a4 += __shfl_down(a4, off);
    }
    if (lane == 0) {
        double v[NE] = {a0, a1, a2, a3, a4};
        int i0 = 0;
        for (int e = 1; e < NE; ++e) if (v[e] > v[i0]) i0 = e;
        int i1 = -1;
        for (int e = 0; e < NE; ++e) {
            if (e == i0) continue;
            if (i1 < 0 || v[e] > v[i1]) i1 = e;
        }
        float e1 = expf((float)(v[i1] - v[i0]));
        float g0 = 1.0f / (1.0f + e1);
        float g1 = e1 * g0;
        int p0 = atomicAdd(&counts[i0], 1);
        btok[i0 * T_TOK + p0] = t;  bgate[i0 * T_TOK + p0] = g0;
        int p1 = atomicAdd(&counts[i1], 1);
        btok[i1 * T_TOK + p1] = t;  bgate[i1 * T_TOK + p1] = g1;
    }
}

// ---------------- fused expert MLP (32x32x16 bf16 MFMA) ----------------
// grid (256, NE), 512 threads (8 waves). Block = BM=64 gathered rows of expert e.
// Per jc (BJ=128 HID cols):
//   step a: h = gelu(x(64x768) @ W1chunk(768x128) + b1): wave = (mt2=wv&1, nt2l=wv>>1),
//           one 32x32 tile per wave, K=768 (48 k-frags, 2 chains).
//   step b: y(64x768) += h(64x128) @ W2chunk(128x768): wave owns out cols
//           [wv*96, wv*96+96) = 3 n-tiles of 32, both m-tiles; K=128 (8 k-frags).
// hs double-buffered -> ONE barrier per jc. xs LDS-resident across all jc.
__global__ __launch_bounds__(512, 2) void expert_kernel(
    const unsigned short* __restrict__ xb, const unsigned short* __restrict__ W1s,
    const unsigned short* __restrict__ W2s, const float* __restrict__ b1,
    const float* __restrict__ b2, const int* __restrict__ counts,
    const int* __restrict__ btok, const float* __restrict__ bgate,
    float* __restrict__ out) {
    __shared__ __align__(16) unsigned short xs[BM][776];      // 99.3 KB (+8 pad)
    __shared__ __align__(16) unsigned short hs[2][BM][136];   // 34.8 KB (+8 pad)
    __shared__ int   st[BM];
    __shared__ float sg[BM];

    const int e = blockIdx.y;
    const int cnt = counts[e];
    const int m0 = blockIdx.x * BM;
    if (m0 >= cnt) return;

    const int tid = threadIdx.x;
    const int wv = tid >> 6, lane = tid & 63;
    const int l31 = lane & 31, lhi = lane >> 5;

    if (tid < BM) {
        int pos = m0 + tid;
        st[tid] = (pos < cnt) ? btok[e * T_TOK + pos] : 0;
        sg[tid] = (pos < cnt) ? bgate[e * T_TOK + pos] : 0.0f;
    }
    __syncthreads();

    // stage x rows (gather) into LDS: 8 threads/row, 96 bf16 each
    {
        int r = tid >> 3, seg = tid & 7;
        const unsigned short* src = xb + (size_t)st[r] * DIM + seg * 96;
        unsigned short* dst = &xs[r][seg * 96];
        #pragma unroll
        for (int i = 0; i < 12; ++i)
            reinterpret_cast<bf16x8*>(dst)[i] =
                reinterpret_cast<const bf16x8*>(src)[i];
    }
    __syncthreads();

    const int mt2  = wv & 1;   // step-a m-tile (32 rows)
    const int nt2l = wv >> 1;  // step-a n-tile within chunk (0..3)

    f32x16 acc[2][3];
    #pragma unroll
    for (int a_ = 0; a_ < 2; ++a_)
        #pragma unroll
        for (int b_ = 0; b_ < 3; ++b_)
            #pragma unroll
            for (int q = 0; q < 16; ++q) acc[a_][b_][q] = 0.0f;

    const unsigned short* arow = &xs[mt2 * 32 + l31][lhi * 8];

    for (int jc = 0; jc < NJC; ++jc) {
        // ---- step a: one 32x32 h tile per wave, K=768 (two chains for ILP)
        f32x16 c0, c1;
        #pragma unroll
        for (int q = 0; q < 16; ++q) { c0[q] = 0.0f; c1[q] = 0.0f; }
        const unsigned short* bpa =
            W1s + ((size_t)((e * 96 + jc * 4 + nt2l) * 48)) * 512 + lane * 8;
        #pragma unroll
        for (int kf = 0; kf < 48; kf += 2) {
            bf16x8 a0 = *reinterpret_cast<const bf16x8*>(arow + kf * 16);
            bf16x8 b0 = *reinterpret_cast<const bf16x8*>(bpa + (size_t)kf * 512);
            c0 = MFMA32(a0, b0, c0);
            bf16x8 a1 = *reinterpret_cast<const bf16x8*>(arow + kf * 16 + 16);
            bf16x8 b1 = *reinterpret_cast<const bf16x8*>(bpa + (size_t)kf * 512 + 512);
            c1 = MFMA32(a1, b1, c1);
        }
        #pragma unroll
        for (int q = 0; q < 16; ++q) c0[q] += c1[q];

        // gelu epilogue -> hs[jc&1]  (32x32 C/D layout: col=lane&31,
        // row=(reg&3)+8*(reg>>2)+4*(lane>>5)  [m74/m101 verified])
        {
            int col = nt2l * 32 + l31;
            float bias = b1[e * HID + jc * BJ + col];
            #pragma unroll
            for (int reg = 0; reg < 16; ++reg) {
                int row = (reg & 3) + 8 * (reg >> 2) + 4 * lhi;
                float v = c0[reg] + bias;
                float gl = 0.5f * v * (1.0f + erff(v * 0.70710678118654752f));
                hs[jc & 1][mt2 * 32 + row][col] = f2bf(gl);
            }
        }
        __syncthreads();

        // ---- step b: acc += h @ W2chunk ; wave owns 3 n-tiles, both m-tiles
        const unsigned short* bpb =
            W2s + ((size_t)((e * 24 + wv * 3) * 192 + jc * 8)) * 512 + lane * 8;
        #pragma unroll
        for (int kf = 0; kf < 8; ++kf) {
            bf16x8 af0 = *reinterpret_cast<const bf16x8*>(
                &hs[jc & 1][l31][kf * 16 + lhi * 8]);
            bf16x8 af1 = *reinterpret_cast<const bf16x8*>(
                &hs[jc & 1][32 + l31][kf * 16 + lhi * 8]);
            #pragma unroll
            for (int i = 0; i < 3; ++i) {
                bf16x8 bv = *reinterpret_cast<const bf16x8*>(
                    bpb + ((size_t)i * 192 + kf) * 512);
                acc[0][i] = MFMA32(af0, bv, acc[0][i]);
                acc[1][i] = MFMA32(af1, bv, acc[1][i]);
            }
        }
    }

    // ---- epilogue: out[t] += g * exp(y + b2)
    #pragma unroll
    for (int mt = 0; mt < 2; ++mt) {
        #pragma unroll
        for (int i = 0; i < 3; ++i) {
            int cg = (wv * 3 + i) * 32 + l31;
            float bias2 = b2[e * DIM + cg];
            #pragma unroll
            for (int reg = 0; reg < 16; ++reg) {
                int row = mt * 32 + (reg & 3) + 8 * (reg >> 2) + 4 * lhi;
                float g = sg[row];
                if (g > 0.0f) {
                    float v = acc[mt][i][reg] + bias2;
                    atomicAdd(out + (size_t)st[row] * DIM + cg, g * expf(v));
                }
            }
        }
    }
}

// ---------------- final: out = log(acc), eps guard ----------------
__global__ void log_kernel(float* __restrict__ out, int n) {
    int i = blockIdx.x * 256 + threadIdx.x;
    if (i < n) {
        float v = out[i];
        out[i] = logf(v == 0.0f ? EPS64 : v);
    }
}

extern "C" void kernel_launch(void* const* d_in, const int* in_sizes, int n_in,
                              void* d_out, int out_size, void* d_ws, size_t ws_size,
                              hipStream_t stream) {
    const float* x  = (const float*)d_in[0];
    const float* wg = (const float*)d_in[1];
    const float* W1 = (const float*)d_in[2];
    const float* b1 = (const float*)d_in[3];
    const float* W2 = (const float*)d_in[4];
    const float* b2 = (const float*)d_in[5];
    float* out = (float*)d_out;

    // workspace layout (~70 MB)
    char* ws = (char*)d_ws;
    int*            counts = (int*)ws;                                   // 256 B
    int*            btok   = (int*)(ws + 256);                           // 320 KB
    float*          bgate  = (float*)(ws + 256 + 327680);                // 320 KB
    unsigned short* xb     = (unsigned short*)(ws + 256 + 2 * 327680);   // 24 MB
    unsigned short* W1s    = xb + (size_t)T_TOK * DIM;                   // 22.5 MB
    unsigned short* W2s    = W1s + (size_t)NE * DIM * HID;               // 22.5 MB

    hipMemsetAsync(counts, 0, 256, stream);
    hipMemsetAsync(out, 0, (size_t)out_size * sizeof(float), stream);

    cast_x_kernel<<<(T_TOK * DIM / 4 + 255) / 256, 256, 0, stream>>>(x, xb);
    prep_w1_kernel<<<NE * 96 * 48 / 4, 256, 0, stream>>>(W1, W1s);
    prep_w2_kernel<<<NE * 24 * 192 / 4, 256, 0, stream>>>(W2, W2s);
    gate_kernel<<<T_TOK / 4, 256, 0, stream>>>(x, wg, counts, btok, bgate);

    expert_kernel<<<dim3(T_TOK / BM, NE), 512, 0, stream>>>(
        xb, W1s, W2s, b1, b2, counts, btok, bgate, out);

    log_kernel<<<(out_size + 255) / 256, 256, 0, stream>>>(out, out_size);
}

// Round 3
// 1189.772 us; speedup vs baseline: 1.6047x; 1.2791x over previous
//
#include <hip/hip_runtime.h>
#include <math.h>

// Problem constants (from reference)
#define T_TOK 16384
#define DIM   768
#define HID   3072
#define NE    5
#define MT    65            // max 128-row m-tiles per expert bucket (cap 8320 rows)
#define HCAP  (MT * 128)
#define EPSF  2.2204460492503131e-16f

typedef short bf16x8  __attribute__((ext_vector_type(8)));   // 8 bf16 in 4 VGPRs
typedef float f32x4   __attribute__((ext_vector_type(4)));
typedef float f32x16  __attribute__((ext_vector_type(16)));

#define MFMA16(A, B, C) __builtin_amdgcn_mfma_f32_16x16x32_bf16((A), (B), (C), 0, 0, 0)
#define MFMA32(A, B, C) __builtin_amdgcn_mfma_f32_32x32x16_bf16((A), (B), (C), 0, 0, 0)

__device__ __forceinline__ unsigned short f2bf(float f) {
    unsigned int u = __float_as_uint(f);
    unsigned int r = (u + 0x7fffu + ((u >> 16) & 1u)) >> 16;  // RNE
    return (unsigned short)r;
}

__device__ __forceinline__ void gld16(const void* g, void* l) {
    __builtin_amdgcn_global_load_lds(
        (const __attribute__((address_space(1))) void*)g,
        (__attribute__((address_space(3))) void*)l, 16, 0, 0);
}

// ---------------- cast x fp32 -> bf16 ----------------
__global__ void cast_x_kernel(const float* __restrict__ x, unsigned short* __restrict__ xb) {
    int i = (blockIdx.x * 256 + threadIdx.x) * 4;
    if (i >= T_TOK * DIM) return;
    float4 v = *reinterpret_cast<const float4*>(x + i);
    ushort4 o;
    o.x = f2bf(v.x); o.y = f2bf(v.y); o.z = f2bf(v.z); o.w = f2bf(v.w);
    *reinterpret_cast<ushort4*>(xb + i) = o;
}

// ---------------- prep: W1 -> LDS-tile-linear, XOR-swizzled bf16 ----------------
// tile t = (e*24 + nb)*12 + kb ; W1p[t*8192 + n*64 + p*8 + j] =
//   bf16( W1[e][ kb*64 + (p^(n&7))*8 + j ][ nb*128 + n ] )
__global__ void prep_w1p(const float* __restrict__ W1, unsigned short* __restrict__ W1p) {
    int idx = blockIdx.x * 256 + threadIdx.x;          // 1,474,560 threads
    if (idx >= NE * 24 * 12 * 128 * 8) return;
    int p = idx & 7;
    int n = (idx >> 3) & 127;
    int t = idx >> 10;
    int kb = t % 12; t /= 12;
    int nb = t % 24; int e = t / 24;
    int klog = kb * 64 + (p ^ (n & 7)) * 8;
    const float* src = W1 + ((size_t)e * DIM + klog) * HID + nb * 128 + n;
    bf16x8 v;
    #pragma unroll
    for (int j = 0; j < 8; ++j) v[j] = (short)f2bf(src[(size_t)j * HID]);
    *reinterpret_cast<bf16x8*>(W1p + (size_t)idx * 8) = v;
}

// tile t = (e*6 + nb)*48 + kb ; W2p[t*8192 + n*64 + p*8 + j] =
//   bf16( W2[e][ kb*64 + (p^(n&7))*8 + j ][ nb*128 + n ] )
__global__ void prep_w2p(const float* __restrict__ W2, unsigned short* __restrict__ W2p) {
    int idx = blockIdx.x * 256 + threadIdx.x;
    if (idx >= NE * 6 * 48 * 128 * 8) return;
    int p = idx & 7;
    int n = (idx >> 3) & 127;
    int t = idx >> 10;
    int kb = t % 48; t /= 48;
    int nb = t % 6; int e = t / 6;
    int klog = kb * 64 + (p ^ (n & 7)) * 8;
    const float* src = W2 + ((size_t)e * HID + klog) * DIM + nb * 128 + n;
    bf16x8 v;
    #pragma unroll
    for (int j = 0; j < 8; ++j) v[j] = (short)f2bf(src[(size_t)j * DIM]);
    *reinterpret_cast<bf16x8*>(W2p + (size_t)idx * 8) = v;
}

// ---------------- gating: fp64 logits, top-2, softmax, bucket scatter ----------------
__global__ void gate_kernel(const float* __restrict__ x, const float* __restrict__ wg,
                            int* __restrict__ counts, int* __restrict__ btok,
                            float* __restrict__ bgate) {
    int wv = threadIdx.x >> 6, lane = threadIdx.x & 63;
    int t = blockIdx.x * 4 + wv;
    double a0 = 0, a1 = 0, a2 = 0, a3 = 0, a4 = 0;
    for (int i = 0; i < 12; ++i) {
        int d = i * 64 + lane;
        double xv = (double)x[(long long)t * DIM + d];
        a0 += xv * (double)wg[d * NE + 0];
        a1 += xv * (double)wg[d * NE + 1];
        a2 += xv * (double)wg[d * NE + 2];
        a3 += xv * (double)wg[d * NE + 3];
        a4 += xv * (double)wg[d * NE + 4];
    }
    for (int off = 32; off; off >>= 1) {
        a0 += __shfl_down(a0, off);
        a1 += __shfl_down(a1, off);
        a2 += __shfl_down(a2, off);
        a3 += __shfl_down(a3, off);
        a4 += __shfl_down(a4, off);
    }
    if (lane == 0) {
        double v[NE] = {a0, a1, a2, a3, a4};
        int i0 = 0;
        for (int e = 1; e < NE; ++e) if (v[e] > v[i0]) i0 = e;
        int i1 = -1;
        for (int e = 0; e < NE; ++e) {
            if (e == i0) continue;
            if (i1 < 0 || v[e] > v[i1]) i1 = e;
        }
        float e1 = expf((float)(v[i1] - v[i0]));
        float g0 = 1.0f / (1.0f + e1);
        float g1 = e1 * g0;
        int p0 = atomicAdd(&counts[i0], 1);
        btok[i0 * T_TOK + p0] = t;  bgate[i0 * T_TOK + p0] = g0;
        int p1 = atomicAdd(&counts[i1], 1);
        btok[i1 * T_TOK + p1] = t;  bgate[i1 * T_TOK + p1] = g1;
    }
}

// ---------------- combo GEMM kernel (m97-style 128x128 tile, BK=64) ----------------
// One launch runs GEMM2(expert g2e, h->out) blocks first, then GEMM1(expert g1e,
// x->h) blocks. 256 threads = 4 waves in a 2x2 (wm,wn) grid; each wave computes
// 64x64 = 4x4 16x16x32 MFMA frags. A and B staged to LDS via global_load_lds
// (16B/lane); LDS tiles are [row(128)][k(64)] with per-row XOR-8 column swizzle
// so fragment ds_read_b128 is <=2-way bank-conflicted (free, m136).
__global__ __launch_bounds__(256, 3) void combo_kernel(
    const unsigned short* __restrict__ xb,
    const unsigned short* __restrict__ W1p,
    const unsigned short* __restrict__ W2p,
    const float* __restrict__ b1, const float* __restrict__ b2,
    const int* __restrict__ counts, const int* __restrict__ btok,
    const float* __restrict__ bgate,
    unsigned short* __restrict__ h0, unsigned short* __restrict__ h1,
    float* __restrict__ out, int g1e, int g2e) {
    __shared__ __align__(16) unsigned short As[128 * 64];   // 16 KB
    __shared__ __align__(16) unsigned short Bs[128 * 64];   // 16 KB
    __shared__ int   sst[128];
    __shared__ float ssg[128];

    const int g2n = (g2e >= 0) ? MT * 6 : 0;
    int bx = blockIdx.x;
    const bool isG2 = bx < g2n;
    int e, mt, nt;
    if (isG2) { e = g2e; mt = bx / 6;  nt = bx % 6; }
    else      { bx -= g2n; e = g1e; mt = bx / 24; nt = bx % 24; }
    const int cnt = counts[e];
    const int m0 = mt * 128;
    if (m0 >= cnt) return;
    unsigned short* hbuf = (e & 1) ? h1 : h0;  // parity ping-pong (g1e=g2e+1 -> disjoint)

    const int tid = threadIdx.x;
    const int wv = tid >> 6, lane = tid & 63;
    const int wm = wv >> 1, wn = wv & 1;
    const int col = lane & 15, quad = lane >> 4;
    const int l8 = lane & 7, r8 = lane >> 3;

    // per-thread global A base pointers (4 DMA instructions per wave per k-step)
    const unsigned short* aptr[4];
    if (isG2) {
        if (tid < 128) {
            int pos = m0 + tid;
            sst[tid] = (pos < cnt) ? btok[e * T_TOK + pos] : 0;
            ssg[tid] = (pos < cnt) ? bgate[e * T_TOK + pos] : 0.0f;
        }
        #pragma unroll
        for (int q = 0; q < 4; ++q) {
            int r = wv * 32 + q * 8 + r8;
            aptr[q] = hbuf + (size_t)(m0 + r) * HID + (l8 ^ r8) * 8;
        }
    } else {
        #pragma unroll
        for (int q = 0; q < 4; ++q) {
            int r = wv * 32 + q * 8 + r8;
            int pos = m0 + r;
            int tok = btok[e * T_TOK + (pos < cnt ? pos : 0)];
            aptr[q] = xb + (size_t)tok * DIM + (l8 ^ r8) * 8;
        }
    }
    const unsigned short* btile = isG2
        ? W2p + ((size_t)(e * 6 + nt)) * 48 * 8192
        : W1p + ((size_t)(e * 24 + nt)) * 12 * 8192;
    const int ksteps = isG2 ? 48 : 12;

    f32x4 acc[4][4];
    #pragma unroll
    for (int i = 0; i < 4; ++i)
        #pragma unroll
        for (int j = 0; j < 4; ++j)
            acc[i][j] = (f32x4){0.f, 0.f, 0.f, 0.f};

    for (int ks = 0; ks < ksteps; ++ks) {
        const unsigned short* bk = btile + (size_t)ks * 8192 + (size_t)wv * 2048 + lane * 8;
        #pragma unroll
        for (int q = 0; q < 4; ++q)
            gld16(aptr[q] + ks * 64, &As[(wv * 4 + q) * 512]);
        #pragma unroll
        for (int q = 0; q < 4; ++q)
            gld16(bk + q * 512, &Bs[(wv * 4 + q) * 512]);
        __syncthreads();
        #pragma unroll
        for (int kf = 0; kf < 2; ++kf) {
            const int p = ((kf * 4 + quad) ^ l8) * 8;
            bf16x8 a[4], b[4];
            #pragma unroll
            for (int i = 0; i < 4; ++i)
                a[i] = *reinterpret_cast<const bf16x8*>(&As[(wm * 64 + i * 16 + col) * 64 + p]);
            #pragma unroll
            for (int i = 0; i < 4; ++i)
                b[i] = *reinterpret_cast<const bf16x8*>(&Bs[(wn * 64 + i * 16 + col) * 64 + p]);
            #pragma unroll
            for (int i = 0; i < 4; ++i)
                #pragma unroll
                for (int j = 0; j < 4; ++j)
                    acc[i][j] = MFMA16(a[i], b[j], acc[i][j]);
        }
        __syncthreads();
    }

    const int nb0 = nt * 128 + wn * 64;
    if (!isG2) {
        // h = gelu(acc + b1), bf16, rows by bucket position
        #pragma unroll
        for (int j = 0; j < 4; ++j) {
            float bias = b1[e * HID + nb0 + j * 16 + col];
            #pragma unroll
            for (int i = 0; i < 4; ++i) {
                #pragma unroll
                for (int r = 0; r < 4; ++r) {
                    int row = m0 + wm * 64 + i * 16 + quad * 4 + r;
                    float v = acc[i][j][r] + bias;
                    float gl = 0.5f * v * (1.0f + erff(v * 0.70710678118654752f));
                    hbuf[(size_t)row * HID + nb0 + j * 16 + col] = f2bf(gl);
                }
            }
        }
    } else {
        // out[t] += g * exp(acc + b2)
        #pragma unroll
        for (int j = 0; j < 4; ++j) {
            float bias = b2[e * DIM + nb0 + j * 16 + col];
            #pragma unroll
            for (int i = 0; i < 4; ++i) {
                #pragma unroll
                for (int r = 0; r < 4; ++r) {
                    int lrow = wm * 64 + i * 16 + quad * 4 + r;
                    float g = ssg[lrow];
                    if (g > 0.0f) {
                        float v = acc[i][j][r] + bias;
                        atomicAdd(out + (size_t)sst[lrow] * DIM + nb0 + j * 16 + col,
                                  g * expf(v));
                    }
                }
            }
        }
    }
}

// ---------------- final: out = log(acc), eps guard ----------------
__global__ void log_kernel(float* __restrict__ out, int n) {
    int i = blockIdx.x * 256 + threadIdx.x;
    if (i < n) {
        float v = out[i];
        out[i] = logf(v == 0.0f ? EPSF : v);
    }
}

// ================= round-2 fallback path (used only if ws too small) =================
__global__ void prep_w1_v2(const float* __restrict__ W1, unsigned short* __restrict__ W1s) {
    int g = blockIdx.x * 4 + (threadIdx.x >> 6);
    int lane = threadIdx.x & 63;
    int kf = g % 48;
    int rest = g / 48;
    int nt2 = rest % 96;
    int e = rest / 96;
    int n = nt2 * 32 + (lane & 31);
    int k0 = kf * 16 + (lane >> 5) * 8;
    const float* src = W1 + ((size_t)e * DIM + k0) * HID + n;
    bf16x8 v;
    #pragma unroll
    for (int j = 0; j < 8; ++j) v[j] = (short)f2bf(src[(size_t)j * HID]);
    *reinterpret_cast<bf16x8*>(W1s + ((size_t)g * 64 + lane) * 8) = v;
}

__global__ void prep_w2_v2(const float* __restrict__ W2, unsigned short* __restrict__ W2s) {
    int g = blockIdx.x * 4 + (threadIdx.x >> 6);
    int lane = threadIdx.x & 63;
    int kf = g % 192;
    int rest = g / 192;
    int nt2 = rest % 24;
    int e = rest / 24;
    int n = nt2 * 32 + (lane & 31);
    int k0 = kf * 16 + (lane >> 5) * 8;
    const float* src = W2 + ((size_t)e * HID + k0) * DIM + n;
    bf16x8 v;
    #pragma unroll
    for (int j = 0; j < 8; ++j) v[j] = (short)f2bf(src[(size_t)j * DIM]);
    *reinterpret_cast<bf16x8*>(W2s + ((size_t)g * 64 + lane) * 8) = v;
}

__global__ __launch_bounds__(512, 2) void expert_v2(
    const unsigned short* __restrict__ xb, const unsigned short* __restrict__ W1s,
    const unsigned short* __restrict__ W2s, const float* __restrict__ b1,
    const float* __restrict__ b2, const int* __restrict__ counts,
    const int* __restrict__ btok, const float* __restrict__ bgate,
    float* __restrict__ out) {
    __shared__ __align__(16) unsigned short xs[64][776];
    __shared__ __align__(16) unsigned short hs[2][64][136];
    __shared__ int   st[64];
    __shared__ float sg[64];

    const int e = blockIdx.y;
    const int cnt = counts[e];
    const int m0 = blockIdx.x * 64;
    if (m0 >= cnt) return;

    const int tid = threadIdx.x;
    const int wv = tid >> 6, lane = tid & 63;
    const int l31 = lane & 31, lhi = lane >> 5;

    if (tid < 64) {
        int pos = m0 + tid;
        st[tid] = (pos < cnt) ? btok[e * T_TOK + pos] : 0;
        sg[tid] = (pos < cnt) ? bgate[e * T_TOK + pos] : 0.0f;
    }
    __syncthreads();
    {
        int r = tid >> 3, seg = tid & 7;
        const unsigned short* src = xb + (size_t)st[r] * DIM + seg * 96;
        unsigned short* dst = &xs[r][seg * 96];
        #pragma unroll
        for (int i = 0; i < 12; ++i)
            reinterpret_cast<bf16x8*>(dst)[i] = reinterpret_cast<const bf16x8*>(src)[i];
    }
    __syncthreads();

    const int mt2 = wv & 1, nt2l = wv >> 1;
    f32x16 acc[2][3];
    #pragma unroll
    for (int a_ = 0; a_ < 2; ++a_)
        #pragma unroll
        for (int b_ = 0; b_ < 3; ++b_)
            #pragma unroll
            for (int q = 0; q < 16; ++q) acc[a_][b_][q] = 0.0f;

    const unsigned short* arow = &xs[mt2 * 32 + l31][lhi * 8];
    for (int jc = 0; jc < 24; ++jc) {
        f32x16 c0, c1;
        #pragma unroll
        for (int q = 0; q < 16; ++q) { c0[q] = 0.0f; c1[q] = 0.0f; }
        const unsigned short* bpa =
            W1s + ((size_t)((e * 96 + jc * 4 + nt2l) * 48)) * 512 + lane * 8;
        #pragma unroll
        for (int kf = 0; kf < 48; kf += 2) {
            bf16x8 a0 = *reinterpret_cast<const bf16x8*>(arow + kf * 16);
            bf16x8 b0 = *reinterpret_cast<const bf16x8*>(bpa + (size_t)kf * 512);
            c0 = MFMA32(a0, b0, c0);
            bf16x8 a1 = *reinterpret_cast<const bf16x8*>(arow + kf * 16 + 16);
            bf16x8 b1 = *reinterpret_cast<const bf16x8*>(bpa + (size_t)kf * 512 + 512);
            c1 = MFMA32(a1, b1, c1);
        }
        #pragma unroll
        for (int q = 0; q < 16; ++q) c0[q] += c1[q];
        {
            int colc = nt2l * 32 + l31;
            float bias = b1[e * HID + jc * 128 + colc];
            #pragma unroll
            for (int reg = 0; reg < 16; ++reg) {
                int row = (reg & 3) + 8 * (reg >> 2) + 4 * lhi;
                float v = c0[reg] + bias;
                float gl = 0.5f * v * (1.0f + erff(v * 0.70710678118654752f));
                hs[jc & 1][mt2 * 32 + row][colc] = f2bf(gl);
            }
        }
        __syncthreads();
        const unsigned short* bpb =
            W2s + ((size_t)((e * 24 + wv * 3) * 192 + jc * 8)) * 512 + lane * 8;
        #pragma unroll
        for (int kf = 0; kf < 8; ++kf) {
            bf16x8 af0 = *reinterpret_cast<const bf16x8*>(&hs[jc & 1][l31][kf * 16 + lhi * 8]);
            bf16x8 af1 = *reinterpret_cast<const bf16x8*>(&hs[jc & 1][32 + l31][kf * 16 + lhi * 8]);
            #pragma unroll
            for (int i = 0; i < 3; ++i) {
                bf16x8 bv = *reinterpret_cast<const bf16x8*>(bpb + ((size_t)i * 192 + kf) * 512);
                acc[0][i] = MFMA32(af0, bv, acc[0][i]);
                acc[1][i] = MFMA32(af1, bv, acc[1][i]);
            }
        }
    }
    #pragma unroll
    for (int mt = 0; mt < 2; ++mt) {
        #pragma unroll
        for (int i = 0; i < 3; ++i) {
            int cg = (wv * 3 + i) * 32 + l31;
            float bias2 = b2[e * DIM + cg];
            #pragma unroll
            for (int reg = 0; reg < 16; ++reg) {
                int row = mt * 32 + (reg & 3) + 8 * (reg >> 2) + 4 * lhi;
                float g = sg[row];
                if (g > 0.0f) {
                    float v = acc[mt][i][reg] + bias2;
                    atomicAdd(out + (size_t)st[row] * DIM + cg, g * expf(v));
                }
            }
        }
    }
}

// =====================================================================

extern "C" void kernel_launch(void* const* d_in, const int* in_sizes, int n_in,
                              void* d_out, int out_size, void* d_ws, size_t ws_size,
                              hipStream_t stream) {
    const float* x  = (const float*)d_in[0];
    const float* wg = (const float*)d_in[1];
    const float* W1 = (const float*)d_in[2];
    const float* b1 = (const float*)d_in[3];
    const float* W2 = (const float*)d_in[4];
    const float* b2 = (const float*)d_in[5];
    float* out = (float*)d_out;

    // workspace layout
    char* ws = (char*)d_ws;
    int*            counts = (int*)ws;                                   // 256 B
    int*            btok   = (int*)(ws + 256);                           // 320 KB
    float*          bgate  = (float*)(ws + 256 + 327680);                // 320 KB
    unsigned short* xb     = (unsigned short*)(ws + 256 + 2 * 327680);   // 24 MB
    unsigned short* W1b    = xb + (size_t)T_TOK * DIM;                   // 22.5 MB
    unsigned short* W2b    = W1b + (size_t)NE * DIM * HID;               // 22.5 MB
    unsigned short* h0     = W2b + (size_t)NE * HID * DIM;               // 48.75 MB
    unsigned short* h1     = h0 + (size_t)HCAP * HID;                    // 48.75 MB

    const size_t need_fast = 256 + 2 * 327680
        + (size_t)T_TOK * DIM * 2 + 2 * (size_t)NE * DIM * HID * 2
        + 2 * (size_t)HCAP * HID * 2;
    const bool fast = ws_size >= need_fast;

    hipMemsetAsync(counts, 0, 256, stream);
    hipMemsetAsync(out, 0, (size_t)out_size * sizeof(float), stream);

    cast_x_kernel<<<(T_TOK * DIM / 4 + 255) / 256, 256, 0, stream>>>(x, xb);
    gate_kernel<<<T_TOK / 4, 256, 0, stream>>>(x, wg, counts, btok, bgate);

    if (fast) {
        prep_w1p<<<(NE * 24 * 12 * 128 * 8 + 255) / 256, 256, 0, stream>>>(W1, W1b);
        prep_w2p<<<(NE * 6 * 48 * 128 * 8 + 255) / 256, 256, 0, stream>>>(W2, W2b);
        for (int s = 0; s < 6; ++s) {
            int g1e = (s <= 4) ? s : -1;
            int g2e = s - 1;
            int nb = (g2e >= 0 ? MT * 6 : 0) + (g1e >= 0 ? MT * 24 : 0);
            combo_kernel<<<nb, 256, 0, stream>>>(xb, W1b, W2b, b1, b2, counts,
                                                 btok, bgate, h0, h1, out, g1e, g2e);
        }
    } else {
        prep_w1_v2<<<NE * 96 * 48 / 4, 256, 0, stream>>>(W1, W1b);
        prep_w2_v2<<<NE * 24 * 192 / 4, 256, 0, stream>>>(W2, W2b);
        expert_v2<<<dim3(T_TOK / 64, NE), 512, 0, stream>>>(
            xb, W1b, W2b, b1, b2, counts, btok, bgate, out);
    }

    log_kernel<<<(out_size + 255) / 256, 256, 0, stream>>>(out, out_size);
}

// Round 4
// 829.000 us; speedup vs baseline: 2.3030x; 1.4352x over previous
//
#include <hip/hip_runtime.h>
#include <math.h>

// Problem constants (from reference)
#define T_TOK 16384
#define DIM   768
#define HID   3072
#define NE    5
#define MT    65            // max 128-row m-tiles per expert bucket (cap 8320 rows)
#define HCAP  (MT * 128)
#define CSTR  32            // counts stride (ints) -> one 128B line per expert
#define EPSF  2.2204460492503131e-16f

typedef short bf16x8  __attribute__((ext_vector_type(8)));   // 8 bf16 in 4 VGPRs
typedef float f32x4   __attribute__((ext_vector_type(4)));
typedef float f32x16  __attribute__((ext_vector_type(16)));

#define MFMA16(A, B, C) __builtin_amdgcn_mfma_f32_16x16x32_bf16((A), (B), (C), 0, 0, 0)
#define MFMA32(A, B, C) __builtin_amdgcn_mfma_f32_32x32x16_bf16((A), (B), (C), 0, 0, 0)

__device__ __forceinline__ unsigned short f2bf(float f) {
    unsigned int u = __float_as_uint(f);
    unsigned int r = (u + 0x7fffu + ((u >> 16) & 1u)) >> 16;  // RNE
    return (unsigned short)r;
}

__device__ __forceinline__ void gld16(const void* g, void* l) {
    __builtin_amdgcn_global_load_lds(
        (const __attribute__((address_space(1))) void*)g,
        (__attribute__((address_space(3))) void*)l, 16, 0, 0);
}

// ---------------- prep: W1 -> LDS-tile-linear, XOR-swizzled bf16 ----------------
// tile t = (e*24 + nb)*12 + kb ; W1p[t*8192 + n*64 + p*8 + j] =
//   bf16( W1[e][ kb*64 + (p^(n&7))*8 + j ][ nb*128 + n ] )
__global__ void prep_w1p(const float* __restrict__ W1, unsigned short* __restrict__ W1p) {
    int idx = blockIdx.x * 256 + threadIdx.x;
    if (idx >= NE * 24 * 12 * 128 * 8) return;
    int p = idx & 7;
    int n = (idx >> 3) & 127;
    int t = idx >> 10;
    int kb = t % 12; t /= 12;
    int nb = t % 24; int e = t / 24;
    int klog = kb * 64 + (p ^ (n & 7)) * 8;
    const float* src = W1 + ((size_t)e * DIM + klog) * HID + nb * 128 + n;
    bf16x8 v;
    #pragma unroll
    for (int j = 0; j < 8; ++j) v[j] = (short)f2bf(src[(size_t)j * HID]);
    *reinterpret_cast<bf16x8*>(W1p + (size_t)idx * 8) = v;
}

// tile t = (e*6 + nb)*48 + kb ; W2p[t*8192 + n*64 + p*8 + j] =
//   bf16( W2[e][ kb*64 + (p^(n&7))*8 + j ][ nb*128 + n ] )
__global__ void prep_w2p(const float* __restrict__ W2, unsigned short* __restrict__ W2p) {
    int idx = blockIdx.x * 256 + threadIdx.x;
    if (idx >= NE * 6 * 48 * 128 * 8) return;
    int p = idx & 7;
    int n = (idx >> 3) & 127;
    int t = idx >> 10;
    int kb = t % 48; t /= 48;
    int nb = t % 6; int e = t / 6;
    int klog = kb * 64 + (p ^ (n & 7)) * 8;
    const float* src = W2 + ((size_t)e * HID + klog) * DIM + nb * 128 + n;
    bf16x8 v;
    #pragma unroll
    for (int j = 0; j < 8; ++j) v[j] = (short)f2bf(src[(size_t)j * DIM]);
    *reinterpret_cast<bf16x8*>(W2p + (size_t)idx * 8) = v;
}

// ---------------- gating + x cast, block-aggregated scatter ----------------
// 256 blocks x 64 tokens. 16 lanes per token-group, each group does 4 tokens.
// fp64 logits (tie-exact vs float64 reference), top-2 + softmax.
// Bucket scatter: LDS atomics for local offsets, then 5 padded global atomics
// per block (no same-line contention), then direct writes.
__global__ __launch_bounds__(256) void gate_kernel(
    const float* __restrict__ x, const float* __restrict__ wg,
    unsigned short* __restrict__ xb, int* __restrict__ counts,
    int* __restrict__ btok, float* __restrict__ bgate) {
    __shared__ int   s_e[2][64];
    __shared__ float s_g[2][64];
    __shared__ int   lcnt[NE];
    __shared__ int   gbase[NE];

    const int tid = threadIdx.x;
    if (tid < NE) lcnt[tid] = 0;
    const int grp = tid >> 4, l16 = tid & 15;
    const int t0 = blockIdx.x * 64 + grp * 4;   // 4 consecutive tokens per group

    double acc[4][NE];
    #pragma unroll
    for (int tt = 0; tt < 4; ++tt)
        #pragma unroll
        for (int e = 0; e < NE; ++e) acc[tt][e] = 0.0;

    for (int i = 0; i < 12; ++i) {
        const int dbase = i * 64 + l16 * 4;
        float4 xv[4];
        #pragma unroll
        for (int tt = 0; tt < 4; ++tt) {
            xv[tt] = *reinterpret_cast<const float4*>(x + (size_t)(t0 + tt) * DIM + dbase);
            // fused cast to bf16 (xb consumed by GEMM1)
            ushort4 o;
            o.x = f2bf(xv[tt].x); o.y = f2bf(xv[tt].y);
            o.z = f2bf(xv[tt].z); o.w = f2bf(xv[tt].w);
            *reinterpret_cast<ushort4*>(xb + (size_t)(t0 + tt) * DIM + dbase) = o;
        }
        #pragma unroll
        for (int j = 0; j < 4; ++j) {
            const int d = dbase + j;
            float w0 = wg[d * NE + 0], w1 = wg[d * NE + 1], w2 = wg[d * NE + 2];
            float w3 = wg[d * NE + 3], w4 = wg[d * NE + 4];
            #pragma unroll
            for (int tt = 0; tt < 4; ++tt) {
                double xd = (double)((&xv[tt].x)[j]);
                acc[tt][0] += xd * (double)w0;
                acc[tt][1] += xd * (double)w1;
                acc[tt][2] += xd * (double)w2;
                acc[tt][3] += xd * (double)w3;
                acc[tt][4] += xd * (double)w4;
            }
        }
    }
    // reduce over the 16 lanes of the group
    #pragma unroll
    for (int off = 8; off; off >>= 1)
        #pragma unroll
        for (int tt = 0; tt < 4; ++tt)
            #pragma unroll
            for (int e = 0; e < NE; ++e)
                acc[tt][e] += __shfl_down(acc[tt][e], off, 16);

    if (l16 == 0) {
        #pragma unroll
        for (int tt = 0; tt < 4; ++tt) {
            double v[NE] = {acc[tt][0], acc[tt][1], acc[tt][2], acc[tt][3], acc[tt][4]};
            int i0 = 0;
            for (int e = 1; e < NE; ++e) if (v[e] > v[i0]) i0 = e;
            int i1 = -1;
            for (int e = 0; e < NE; ++e) {
                if (e == i0) continue;
                if (i1 < 0 || v[e] > v[i1]) i1 = e;
            }
            float e1 = expf((float)(v[i1] - v[i0]));
            float g0 = 1.0f / (1.0f + e1);
            int li = grp * 4 + tt;
            s_e[0][li] = i0;  s_g[0][li] = g0;
            s_e[1][li] = i1;  s_g[1][li] = e1 * g0;
        }
    }
    __syncthreads();

    int mye = 0, myoff = 0, mytok = 0;
    float myg = 0.0f;
    if (tid < 128) {
        int li = tid >> 1, which = tid & 1;
        mye = s_e[which][li];
        myg = s_g[which][li];
        mytok = blockIdx.x * 64 + li;
        myoff = atomicAdd(&lcnt[mye], 1);
    }
    __syncthreads();
    if (tid < NE) gbase[tid] = atomicAdd(&counts[tid * CSTR], lcnt[tid]);
    __syncthreads();
    if (tid < 128) {
        int p = gbase[mye] + myoff;
        btok[mye * T_TOK + p] = mytok;
        bgate[mye * T_TOK + p] = myg;
    }
}

// ---------------- combo GEMM kernel (m97-style 128x128 tile, BK=64) ----------------
__global__ __launch_bounds__(256, 3) void combo_kernel(
    const unsigned short* __restrict__ xb,
    const unsigned short* __restrict__ W1p,
    const unsigned short* __restrict__ W2p,
    const float* __restrict__ b1, const float* __restrict__ b2,
    const int* __restrict__ counts, const int* __restrict__ btok,
    const float* __restrict__ bgate,
    unsigned short* __restrict__ h0, unsigned short* __restrict__ h1,
    float* __restrict__ out, int g1e, int g2e) {
    __shared__ __align__(16) unsigned short As[128 * 64];   // 16 KB
    __shared__ __align__(16) unsigned short Bs[128 * 64];   // 16 KB
    __shared__ int   sst[128];
    __shared__ float ssg[128];

    const int g2n = (g2e >= 0) ? MT * 6 : 0;
    int bx = blockIdx.x;
    const bool isG2 = bx < g2n;
    int e, mt, nt;
    if (isG2) { e = g2e; mt = bx / 6;  nt = bx % 6; }
    else      { bx -= g2n; e = g1e; mt = bx / 24; nt = bx % 24; }
    const int cnt = counts[e * CSTR];
    const int m0 = mt * 128;
    if (m0 >= cnt) return;
    unsigned short* hbuf = (e & 1) ? h1 : h0;  // parity ping-pong (g1e=g2e+1 -> disjoint)

    const int tid = threadIdx.x;
    const int wv = tid >> 6, lane = tid & 63;
    const int wm = wv >> 1, wn = wv & 1;
    const int col = lane & 15, quad = lane >> 4;
    const int l8 = lane & 7, r8 = lane >> 3;

    const unsigned short* aptr[4];
    if (isG2) {
        if (tid < 128) {
            int pos = m0 + tid;
            sst[tid] = (pos < cnt) ? btok[e * T_TOK + pos] : 0;
            ssg[tid] = (pos < cnt) ? bgate[e * T_TOK + pos] : 0.0f;
        }
        #pragma unroll
        for (int q = 0; q < 4; ++q) {
            int r = wv * 32 + q * 8 + r8;
            aptr[q] = hbuf + (size_t)(m0 + r) * HID + (l8 ^ r8) * 8;
        }
    } else {
        #pragma unroll
        for (int q = 0; q < 4; ++q) {
            int r = wv * 32 + q * 8 + r8;
            int pos = m0 + r;
            int tok = btok[e * T_TOK + (pos < cnt ? pos : 0)];
            aptr[q] = xb + (size_t)tok * DIM + (l8 ^ r8) * 8;
        }
    }
    const unsigned short* btile = isG2
        ? W2p + ((size_t)(e * 6 + nt)) * 48 * 8192
        : W1p + ((size_t)(e * 24 + nt)) * 12 * 8192;
    const int ksteps = isG2 ? 48 : 12;

    f32x4 acc[4][4];
    #pragma unroll
    for (int i = 0; i < 4; ++i)
        #pragma unroll
        for (int j = 0; j < 4; ++j)
            acc[i][j] = (f32x4){0.f, 0.f, 0.f, 0.f};

    for (int ks = 0; ks < ksteps; ++ks) {
        const unsigned short* bk = btile + (size_t)ks * 8192 + (size_t)wv * 2048 + lane * 8;
        #pragma unroll
        for (int q = 0; q < 4; ++q)
            gld16(aptr[q] + ks * 64, &As[(wv * 4 + q) * 512]);
        #pragma unroll
        for (int q = 0; q < 4; ++q)
            gld16(bk + q * 512, &Bs[(wv * 4 + q) * 512]);
        __syncthreads();
        #pragma unroll
        for (int kf = 0; kf < 2; ++kf) {
            const int p = ((kf * 4 + quad) ^ l8) * 8;
            bf16x8 a[4], b[4];
            #pragma unroll
            for (int i = 0; i < 4; ++i)
                a[i] = *reinterpret_cast<const bf16x8*>(&As[(wm * 64 + i * 16 + col) * 64 + p]);
            #pragma unroll
            for (int i = 0; i < 4; ++i)
                b[i] = *reinterpret_cast<const bf16x8*>(&Bs[(wn * 64 + i * 16 + col) * 64 + p]);
            #pragma unroll
            for (int i = 0; i < 4; ++i)
                #pragma unroll
                for (int j = 0; j < 4; ++j)
                    acc[i][j] = MFMA16(a[i], b[j], acc[i][j]);
        }
        __syncthreads();
    }

    const int nb0 = nt * 128 + wn * 64;
    if (!isG2) {
        #pragma unroll
        for (int j = 0; j < 4; ++j) {
            float bias = b1[e * HID + nb0 + j * 16 + col];
            #pragma unroll
            for (int i = 0; i < 4; ++i) {
                #pragma unroll
                for (int r = 0; r < 4; ++r) {
                    int row = m0 + wm * 64 + i * 16 + quad * 4 + r;
                    float v = acc[i][j][r] + bias;
                    float gl = 0.5f * v * (1.0f + erff(v * 0.70710678118654752f));
                    hbuf[(size_t)row * HID + nb0 + j * 16 + col] = f2bf(gl);
                }
            }
        }
    } else {
        #pragma unroll
        for (int j = 0; j < 4; ++j) {
            float bias = b2[e * DIM + nb0 + j * 16 + col];
            #pragma unroll
            for (int i = 0; i < 4; ++i) {
                #pragma unroll
                for (int r = 0; r < 4; ++r) {
                    int lrow = wm * 64 + i * 16 + quad * 4 + r;
                    float g = ssg[lrow];
                    if (g > 0.0f) {
                        float v = acc[i][j][r] + bias;
                        atomicAdd(out + (size_t)sst[lrow] * DIM + nb0 + j * 16 + col,
                                  g * expf(v));
                    }
                }
            }
        }
    }
}

// ---------------- final: out = log(acc), eps guard ----------------
__global__ void log_kernel(float* __restrict__ out, int n) {
    int i = blockIdx.x * 256 + threadIdx.x;
    if (i < n) {
        float v = out[i];
        out[i] = logf(v == 0.0f ? EPSF : v);
    }
}

// ================= round-2 fallback path (used only if ws too small) =================
__global__ void prep_w1_v2(const float* __restrict__ W1, unsigned short* __restrict__ W1s) {
    int g = blockIdx.x * 4 + (threadIdx.x >> 6);
    int lane = threadIdx.x & 63;
    int kf = g % 48;
    int rest = g / 48;
    int nt2 = rest % 96;
    int e = rest / 96;
    int n = nt2 * 32 + (lane & 31);
    int k0 = kf * 16 + (lane >> 5) * 8;
    const float* src = W1 + ((size_t)e * DIM + k0) * HID + n;
    bf16x8 v;
    #pragma unroll
    for (int j = 0; j < 8; ++j) v[j] = (short)f2bf(src[(size_t)j * HID]);
    *reinterpret_cast<bf16x8*>(W1s + ((size_t)g * 64 + lane) * 8) = v;
}

__global__ void prep_w2_v2(const float* __restrict__ W2, unsigned short* __restrict__ W2s) {
    int g = blockIdx.x * 4 + (threadIdx.x >> 6);
    int lane = threadIdx.x & 63;
    int kf = g % 192;
    int rest = g / 192;
    int nt2 = rest % 24;
    int e = rest / 24;
    int n = nt2 * 32 + (lane & 31);
    int k0 = kf * 16 + (lane >> 5) * 8;
    const float* src = W2 + ((size_t)e * HID + k0) * DIM + n;
    bf16x8 v;
    #pragma unroll
    for (int j = 0; j < 8; ++j) v[j] = (short)f2bf(src[(size_t)j * DIM]);
    *reinterpret_cast<bf16x8*>(W2s + ((size_t)g * 64 + lane) * 8) = v;
}

__global__ __launch_bounds__(512, 2) void expert_v2(
    const unsigned short* __restrict__ xb, const unsigned short* __restrict__ W1s,
    const unsigned short* __restrict__ W2s, const float* __restrict__ b1,
    const float* __restrict__ b2, const int* __restrict__ counts,
    const int* __restrict__ btok, const float* __restrict__ bgate,
    float* __restrict__ out) {
    __shared__ __align__(16) unsigned short xs[64][776];
    __shared__ __align__(16) unsigned short hs[2][64][136];
    __shared__ int   st[64];
    __shared__ float sg[64];

    const int e = blockIdx.y;
    const int cnt = counts[e * CSTR];
    const int m0 = blockIdx.x * 64;
    if (m0 >= cnt) return;

    const int tid = threadIdx.x;
    const int wv = tid >> 6, lane = tid & 63;
    const int l31 = lane & 31, lhi = lane >> 5;

    if (tid < 64) {
        int pos = m0 + tid;
        st[tid] = (pos < cnt) ? btok[e * T_TOK + pos] : 0;
        sg[tid] = (pos < cnt) ? bgate[e * T_TOK + pos] : 0.0f;
    }
    __syncthreads();
    {
        int r = tid >> 3, seg = tid & 7;
        const unsigned short* src = xb + (size_t)st[r] * DIM + seg * 96;
        unsigned short* dst = &xs[r][seg * 96];
        #pragma unroll
        for (int i = 0; i < 12; ++i)
            reinterpret_cast<bf16x8*>(dst)[i] = reinterpret_cast<const bf16x8*>(src)[i];
    }
    __syncthreads();

    const int mt2 = wv & 1, nt2l = wv >> 1;
    f32x16 acc[2][3];
    #pragma unroll
    for (int a_ = 0; a_ < 2; ++a_)
        #pragma unroll
        for (int b_ = 0; b_ < 3; ++b_)
            #pragma unroll
            for (int q = 0; q < 16; ++q) acc[a_][b_][q] = 0.0f;

    const unsigned short* arow = &xs[mt2 * 32 + l31][lhi * 8];
    for (int jc = 0; jc < 24; ++jc) {
        f32x16 c0, c1;
        #pragma unroll
        for (int q = 0; q < 16; ++q) { c0[q] = 0.0f; c1[q] = 0.0f; }
        const unsigned short* bpa =
            W1s + ((size_t)((e * 96 + jc * 4 + nt2l) * 48)) * 512 + lane * 8;
        #pragma unroll
        for (int kf = 0; kf < 48; kf += 2) {
            bf16x8 a0 = *reinterpret_cast<const bf16x8*>(arow + kf * 16);
            bf16x8 b0 = *reinterpret_cast<const bf16x8*>(bpa + (size_t)kf * 512);
            c0 = MFMA32(a0, b0, c0);
            bf16x8 a1 = *reinterpret_cast<const bf16x8*>(arow + kf * 16 + 16);
            bf16x8 b1 = *reinterpret_cast<const bf16x8*>(bpa + (size_t)kf * 512 + 512);
            c1 = MFMA32(a1, b1, c1);
        }
        #pragma unroll
        for (int q = 0; q < 16; ++q) c0[q] += c1[q];
        {
            int colc = nt2l * 32 + l31;
            float bias = b1[e * HID + jc * 128 + colc];
            #pragma unroll
            for (int reg = 0; reg < 16; ++reg) {
                int row = (reg & 3) + 8 * (reg >> 2) + 4 * lhi;
                float v = c0[reg] + bias;
                float gl = 0.5f * v * (1.0f + erff(v * 0.70710678118654752f));
                hs[jc & 1][mt2 * 32 + row][colc] = f2bf(gl);
            }
        }
        __syncthreads();
        const unsigned short* bpb =
            W2s + ((size_t)((e * 24 + wv * 3) * 192 + jc * 8)) * 512 + lane * 8;
        #pragma unroll
        for (int kf = 0; kf < 8; ++kf) {
            bf16x8 af0 = *reinterpret_cast<const bf16x8*>(&hs[jc & 1][l31][kf * 16 + lhi * 8]);
            bf16x8 af1 = *reinterpret_cast<const bf16x8*>(&hs[jc & 1][32 + l31][kf * 16 + lhi * 8]);
            #pragma unroll
            for (int i = 0; i < 3; ++i) {
                bf16x8 bv = *reinterpret_cast<const bf16x8*>(bpb + ((size_t)i * 192 + kf) * 512);
                acc[0][i] = MFMA32(af0, bv, acc[0][i]);
                acc[1][i] = MFMA32(af1, bv, acc[1][i]);
            }
        }
    }
    #pragma unroll
    for (int mt = 0; mt < 2; ++mt) {
        #pragma unroll
        for (int i = 0; i < 3; ++i) {
            int cg = (wv * 3 + i) * 32 + l31;
            float bias2 = b2[e * DIM + cg];
            #pragma unroll
            for (int reg = 0; reg < 16; ++reg) {
                int row = mt * 32 + (reg & 3) + 8 * (reg >> 2) + 4 * lhi;
                float g = sg[row];
                if (g > 0.0f) {
                    float v = acc[mt][i][reg] + bias2;
                    atomicAdd(out + (size_t)st[row] * DIM + cg, g * expf(v));
                }
            }
        }
    }
}

// =====================================================================

extern "C" void kernel_launch(void* const* d_in, const int* in_sizes, int n_in,
                              void* d_out, int out_size, void* d_ws, size_t ws_size,
                              hipStream_t stream) {
    const float* x  = (const float*)d_in[0];
    const float* wg = (const float*)d_in[1];
    const float* W1 = (const float*)d_in[2];
    const float* b1 = (const float*)d_in[3];
    const float* W2 = (const float*)d_in[4];
    const float* b2 = (const float*)d_in[5];
    float* out = (float*)d_out;

    // workspace layout
    char* ws = (char*)d_ws;
    int*            counts = (int*)ws;                                   // 5*128B padded
    int*            btok   = (int*)(ws + 1024);                          // 320 KB
    float*          bgate  = (float*)(ws + 1024 + 327680);               // 320 KB
    unsigned short* xb     = (unsigned short*)(ws + 1024 + 2 * 327680);  // 24 MB
    unsigned short* W1b    = xb + (size_t)T_TOK * DIM;                   // 22.5 MB
    unsigned short* W2b    = W1b + (size_t)NE * DIM * HID;               // 22.5 MB
    unsigned short* h0     = W2b + (size_t)NE * HID * DIM;               // 48.75 MB
    unsigned short* h1     = h0 + (size_t)HCAP * HID;                    // 48.75 MB

    const size_t need_fast = 1024 + 2 * 327680
        + (size_t)T_TOK * DIM * 2 + 2 * (size_t)NE * DIM * HID * 2
        + 2 * (size_t)HCAP * HID * 2;
    const bool fast = ws_size >= need_fast;

    hipMemsetAsync(counts, 0, 1024, stream);
    hipMemsetAsync(out, 0, (size_t)out_size * sizeof(float), stream);

    gate_kernel<<<T_TOK / 64, 256, 0, stream>>>(x, wg, xb, counts, btok, bgate);

    if (fast) {
        prep_w1p<<<(NE * 24 * 12 * 128 * 8 + 255) / 256, 256, 0, stream>>>(W1, W1b);
        prep_w2p<<<(NE * 6 * 48 * 128 * 8 + 255) / 256, 256, 0, stream>>>(W2, W2b);
        for (int s = 0; s < 6; ++s) {
            int g1e = (s <= 4) ? s : -1;
            int g2e = s - 1;
            int nb = (g2e >= 0 ? MT * 6 : 0) + (g1e >= 0 ? MT * 24 : 0);
            combo_kernel<<<nb, 256, 0, stream>>>(xb, W1b, W2b, b1, b2, counts,
                                                 btok, bgate, h0, h1, out, g1e, g2e);
        }
    } else {
        prep_w1_v2<<<NE * 96 * 48 / 4, 256, 0, stream>>>(W1, W1b);
        prep_w2_v2<<<NE * 24 * 192 / 4, 256, 0, stream>>>(W2, W2b);
        expert_v2<<<dim3(T_TOK / 64, NE), 512, 0, stream>>>(
            xb, W1b, W2b, b1, b2, counts, btok, bgate, out);
    }

    log_kernel<<<(out_size + 255) / 256, 256, 0, stream>>>(out, out_size);
}